// Round 9
// baseline (476.977 us; speedup 1.0000x reference)
//
#include <hip/hip_runtime.h>
#include <hip/hip_fp16.h>
#include <math.h>

// Problem constants
#define B 4
#define C 21
#define NP 11               // f16 channel pairs (ch 2k, 2k+1; pair 10 high = pad)
#define H 256
#define W 256
#define HW (H*W)            // 65536
#define NPIX (B*HW)         // 262144
#define NB2 (B*NP*HW)       // 2883584 packed uint elements

// update tile: 16 wide x 48 tall, 384 threads, 2 rows per thread
#define TSX 16
#define TSY 48
#define R 6
#define HXC 28              // halo cols
#define HYR 60              // halo rows
#define NSU (HXC*HYR)       // 1680 records
#define YT 6                // ceil(256/48) y-tiles (last is partial)
#define UBLK (B*16*YT)      // 384 update blocks

#define C2F ((float)(1.4426950408889634 / 338.0))   // log2(e)/338
#define L2E 1.4426950408889634f

// Gaussian-fused kernel geometry
#define GOY 64
#define GTR (GOY + 18)      // 82 T rows
#define GTS 17              // padded quad stride

union U4 { uint4 u; __half2 h[4]; };
union Hu { unsigned int u32; __half2 h; };

__device__ __forceinline__ float fexp2(float x) {
    float r;
    asm("v_exp_f32 %0, %1" : "=v"(r) : "v"(x));
    return r;
}

// ---------------------------------------------------------------------------
// Gaussian taps: kt[0..18] normalized (sigma=3), kt[19]=w0, kt[20]=1-w0
__global__ void k_ktab(float* __restrict__ kt) {
    if (threadIdx.x == 0) {
        float e[19]; float s = 0.f;
        for (int i = 0; i < 19; ++i) {
            double d = (double)(i - 9);
            e[i] = (float)exp(-(d*d) / 18.0);
            s += e[i];
        }
        for (int i = 0; i < 19; ++i) kt[i] = e[i] / s;
        float k9 = e[9] / s;
        kt[19] = k9 * k9;
        kt[20] = 1.f - k9 * k9;
    }
}

// ---------------------------------------------------------------------------
// Pre-quantize image once into packed halves: (r,g),(b,0) — integers 0..255
__global__ __launch_bounds__(256) void k_prep(const float* __restrict__ img,
                                              uint2* __restrict__ IQ2) {
    int p = blockIdx.x * 256 + threadIdx.x;
    int b = p >> 16, g = p & (HW - 1);
    const float* ib = img + (size_t)b * 3 * HW + g;
    float r  = floorf(fminf(fmaxf(ib[0]    * 255.f, 0.f), 255.f));
    float gg = floorf(fminf(fmaxf(ib[HW]   * 255.f, 0.f), 255.f));
    float bb = floorf(fminf(fmaxf(ib[2*HW] * 255.f, 0.f), 255.f));
    Hu rg; rg.h = __floats2half2_rn(r, gg);
    Hu b0; b0.h = __floats2half2_rn(bb, 0.f);
    IQ2[p] = make_uint2(rg.u32, b0.u32);
}

// ---------------------------------------------------------------------------
// Init: U = -log(clip(softmax(logits),1e-5,1)) packed f16; Q0 = softmax(-U) packed f16
__global__ __launch_bounds__(256) void k_init(const float* __restrict__ logits,
                                              unsigned int* __restrict__ Upk,
                                              unsigned int* __restrict__ Qp) {
    int p = blockIdx.x * 256 + threadIdx.x;
    int b = p >> 16, g = p & (HW - 1);
    const float* lp = logits + (size_t)b * C * HW + g;

    float v[C];
    float m = -1e30f;
#pragma unroll
    for (int c = 0; c < C; ++c) { v[c] = lp[c*HW]; m = fmaxf(m, v[c]); }
    float s = 0.f;
#pragma unroll
    for (int c = 0; c < C; ++c) { v[c] = __expf(v[c] - m); s += v[c]; }
    float inv = 1.f / s;

    float u[C];
    float m2 = -1e30f;
#pragma unroll
    for (int c = 0; c < C; ++c) {
        float sm = fminf(fmaxf(v[c] * inv, 1e-5f), 1.f);
        float uu = -__logf(sm);
        u[c] = uu;
        m2 = fmaxf(m2, -uu);
    }
    float s2 = 0.f;
    float q[C];
#pragma unroll
    for (int c = 0; c < C; ++c) { q[c] = __expf(-u[c] - m2); s2 += q[c]; }
    float inv2 = 1.f / s2;

    unsigned int* Ub = Upk + (size_t)b * NP * HW + g;
    unsigned int* Qb = Qp + (size_t)b * NP * HW + g;
#pragma unroll
    for (int k = 0; k < NP; ++k) {
        float ua = u[2*k];
        float ub = (2*k + 1 < C) ? u[2*k + 1] : 0.f;
        Hu xu; xu.h = __floats2half2_rn(ua, ub);
        Ub[k*HW] = xu.u32;
        float qa = q[2*k] * inv2;
        float qb = (2*k + 1 < C) ? q[2*k + 1] * inv2 : 0.f;
        Hu xq; xq.h = __floats2half2_rn(qa, qb);
        Qb[k*HW] = xq.u32;
    }
}

// ---------------------------------------------------------------------------
// Fused separable Gaussian + message: MG = (conv - w0*Q)*(1/(1-w0)).
__global__ __launch_bounds__(256) void k_gauss(const unsigned int* __restrict__ Q,
                                               unsigned int* __restrict__ MG,
                                               const float* __restrict__ kt) {
    __shared__ uint4 T[GTR * GTS];
    __shared__ float kf[21];

    int tid = threadIdx.x;
    if (tid < 21) kf[tid] = kt[tid];
    __syncthreads();

    __half2 kh[19];
#pragma unroll
    for (int j = 0; j < 19; ++j) kh[j] = __float2half2_rn(kf[j]);

    int blk = blockIdx.x;
    int pl  = blk >> 4;
    int sub = blk & 15;
    int y0 = (sub >> 2) * GOY;
    int x0 = (sub & 3) * 64;
    const unsigned int* base = Q + (size_t)pl * HW;

    for (int s = tid; s < GTR * 16; s += 256) {
        int row = s >> 4;
        int q   = s & 15;
        int yy = y0 + row - 9;
        U4 o;
        o.u = make_uint4(0u, 0u, 0u, 0u);
        if ((unsigned)yy < (unsigned)H) {
            int xb = x0 + q * 4;
            const unsigned int* rp = base + yy * W;
            U4 ch[7];
#pragma unroll
            for (int c2 = 0; c2 < 7; ++c2) {
                int xq = xb - 12 + c2 * 4;
                if ((unsigned)xq < (unsigned)W) ch[c2].u = *(const uint4*)(rp + xq);
                else ch[c2].u = make_uint4(0u, 0u, 0u, 0u);
            }
            const __half2* v = (const __half2*)ch;
#pragma unroll
            for (int i = 0; i < 4; ++i) {
                __half2 acc = __float2half2_rn(0.f);
#pragma unroll
                for (int j = 0; j < 19; ++j) acc = __hfma2(kh[j], v[i + 3 + j], acc);
                o.h[i] = acc;
            }
        }
        T[row * GTS + q] = o.u;
    }
    __syncthreads();

    __half2 nw0  = __float2half2_rn(-kf[19]);
    __half2 inv1 = __float2half2_rn(1.f / kf[20]);
    int q  = tid & 15;
    int rg = tid >> 4;
    int r0 = rg * 4;

    __half2 acc[4][4];
#pragma unroll
    for (int i = 0; i < 4; ++i)
#pragma unroll
        for (int qd = 0; qd < 4; ++qd) acc[i][qd] = __float2half2_rn(0.f);

#pragma unroll
    for (int j = 0; j < 22; ++j) {
        U4 f; f.u = T[(r0 + j) * GTS + q];
#pragma unroll
        for (int i = 0; i < 4; ++i) {
            int tap = j - i;
            if (tap >= 0 && tap <= 18) {
#pragma unroll
                for (int qd = 0; qd < 4; ++qd)
                    acc[i][qd] = __hfma2(kh[tap], f.h[qd], acc[i][qd]);
            }
        }
    }

#pragma unroll
    for (int i = 0; i < 4; ++i) {
        size_t e = (size_t)pl * HW + (y0 + r0 + i) * W + x0 + q * 4;
        U4 qq; qq.u = *(const uint4*)(Q + e);
        U4 o;
#pragma unroll
        for (int qd = 0; qd < 4; ++qd)
            o.h[qd] = __hmul2(__hfma2(nw0, qq.h[qd], acc[i][qd]), inv1);
        *(uint4*)(MG + e) = o.u;
    }
}

// ---------------------------------------------------------------------------
// Bilateral message + mean-field update (2 px/thread in y; 384 threads,
// 16x48 tile -> 80.6KB LDS -> 2 blocks/CU = 12 waves/CU).
__global__ __launch_bounds__(384, 3) void k_update(const unsigned int* __restrict__ Q,
                                                   const unsigned int* __restrict__ Upk,
                                                   const unsigned int* __restrict__ MG,
                                                   const uint2* __restrict__ IQ2,
                                                   unsigned int* __restrict__ Qn,
                                                   const int* __restrict__ labels,
                                                   float* __restrict__ part) {
    __shared__ uint4 LA[NSU];
    __shared__ uint4 LB[NSU];
    __shared__ uint4 LC[NSU];
    __shared__ float red[6];

    int blk = blockIdx.x;
    int b = blk / (16 * YT);
    int tile = blk - b * 16 * YT;
    int ty0 = (tile >> 4) * TSY;          // 0,48,...,240 (last partial)
    int tx0 = (tile & 15) * TSX;
    int tid = threadIdx.x;

    const unsigned int* Qb = Q + (size_t)b * NP * HW;
    const uint2* Ib = IQ2 + (size_t)b * HW;

    for (int s = tid; s < NSU; s += 384) {
        int ly = s / HXC;
        int lx = s - ly * HXC;
        int gy = ty0 + ly - R;
        int gx = tx0 + lx - R;
        bool in = ((unsigned)gy < (unsigned)H) && ((unsigned)gx < (unsigned)W);
        int g = gy * W + gx;
        unsigned int u[NP];
#pragma unroll
        for (int k = 0; k < NP; ++k) u[k] = in ? Qb[k*HW + g] : 0u;
        uint2 rgb = in ? Ib[g] : make_uint2(0u, 0u);
        LA[s] = make_uint4(u[0], u[1], u[2], u[3]);
        LB[s] = make_uint4(u[4], u[5], u[6], u[7]);
        unsigned int c2 = (u[10] & 0xffffu) | (rgb.x << 16);   // (ch20, r)
        unsigned int c3 = (rgb.x >> 16) | (rgb.y << 16);       // (g, b)
        LC[s] = make_uint4(u[8], u[9], c2, c3);
    }
    __syncthreads();

    int x = tid & 15;
    int ry = tid >> 4;                // 0..23 -> rows 2ry, 2ry+1
    int r0 = 2 * ry;
    int cp0 = (r0 + R) * HXC + x + R;
    int row0 = ty0 + r0;
    int g0 = row0 * W + (tx0 + x);
    bool v0ok = row0 < H, v1ok = (row0 + 1) < H;

    // --- epilogue prefetch: issue U/MG loads before the tap loop ---
    const unsigned int* Ub = Upk + (size_t)b * NP * HW;
    const unsigned int* Mb = MG + (size_t)b * NP * HW;
    int gp0 = v0ok ? g0 : 0, gp1 = v1ok ? g0 + W : 0;
    unsigned int pfU[2][NP], pfM[2][NP];
#pragma unroll
    for (int k = 0; k < NP; ++k) {
        pfU[0][k] = Ub[k*HW + gp0];   pfM[0][k] = Mb[k*HW + gp0];
        pfU[1][k] = Ub[k*HW + gp1];   pfM[1][k] = Mb[k*HW + gp1];
    }

    float cr0, cg0, cb0, cr1, cg1, cb1;
    {
        U4 cc; cc.u = LC[cp0];
        Hu hz; hz.u32 = cc.u.z;  Hu hw2; hw2.u32 = cc.u.w;
        cr0 = __half2float(__high2half(hz.h));
        cg0 = __half2float(__low2half(hw2.h));
        cb0 = __half2float(__high2half(hw2.h));
        cc.u = LC[cp0 + HXC];
        hz.u32 = cc.u.z;  hw2.u32 = cc.u.w;
        cr1 = __half2float(__high2half(hz.h));
        cg1 = __half2float(__low2half(hw2.h));
        cb1 = __half2float(__high2half(hw2.h));
    }
    float DCr = cr1 - cr0, DCg = cg1 - cg0, DCb = cb1 - cb0;
    float DR2 = 2.f * DCr, DG2 = 2.f * DCg, DB2 = 2.f * DCb;
    float DC2 = DCr*DCr + DCg*DCg + DCb*DCb;

    float kxl[13];
#pragma unroll
    for (int j = 0; j < 13; ++j)
        kxl[j] = -(float)((j - 6) * (j - 6)) * C2F;

    __half2 m0[NP], m1[NP];
#pragma unroll
    for (int k = 0; k < NP; ++k) { m0[k] = __float2half2_rn(0.f); m1[k] = m0[k]; }
    float ws0 = 0.f, ws1 = 0.f;

    for (int dyy = 0; dyy < 14; ++dyy) {
        int rowb = (r0 + dyy) * HXC + x;
        int t0 = dyy - 6, t1 = dyy - 7;
        float a0 = (dyy <= 12) ? -(float)(t0*t0) * C2F : -1e30f;
        float a1 = (dyy >= 1)  ? -(float)(t1*t1) * C2F : -1e30f;
        float rowA0[13], rowA1[13];
#pragma unroll
        for (int j = 0; j < 13; ++j) { rowA0[j] = a0 + kxl[j]; rowA1[j] = a1 + kxl[j]; }
        if (dyy == 6) rowA0[6] = -1e30f;   // exact center exclusion (w=0)
        if (dyy == 7) rowA1[6] = -1e30f;
#pragma unroll
        for (int dxx = 0; dxx < 13; ++dxx) {
            int p = rowb + dxx;
            U4 A, Bq, Cq;
            A.u  = LA[p];
            Bq.u = LB[p];
            Cq.u = LC[p];
            Hu hz; hz.u32 = Cq.u.z;  Hu hw2; hw2.u32 = Cq.u.w;
            float pr = __half2float(__high2half(hz.h));
            float pg = __half2float(__low2half(hw2.h));
            float pb = __half2float(__high2half(hw2.h));
            float d0r = cr0 - pr, d0g = cg0 - pg, d0b = cb0 - pb;
            float ss0 = fmaf(d0r, d0r, fmaf(d0g, d0g, d0b * d0b));
            float ss1 = fmaf(DR2, d0r, fmaf(DG2, d0g, fmaf(DB2, d0b, ss0 + DC2)));
            float w0 = fexp2(fmaf(ss0, -C2F, rowA0[dxx]));
            float w1 = fexp2(fmaf(ss1, -C2F, rowA1[dxx]));
            ws0 += w0; ws1 += w1;
            __half2 wh0 = __float2half2_rn(w0);
            __half2 wh1 = __float2half2_rn(w1);
            m0[0] = __hfma2(wh0, A.h[0], m0[0]);   m1[0] = __hfma2(wh1, A.h[0], m1[0]);
            m0[1] = __hfma2(wh0, A.h[1], m0[1]);   m1[1] = __hfma2(wh1, A.h[1], m1[1]);
            m0[2] = __hfma2(wh0, A.h[2], m0[2]);   m1[2] = __hfma2(wh1, A.h[2], m1[2]);
            m0[3] = __hfma2(wh0, A.h[3], m0[3]);   m1[3] = __hfma2(wh1, A.h[3], m1[3]);
            m0[4] = __hfma2(wh0, Bq.h[0], m0[4]);  m1[4] = __hfma2(wh1, Bq.h[0], m1[4]);
            m0[5] = __hfma2(wh0, Bq.h[1], m0[5]);  m1[5] = __hfma2(wh1, Bq.h[1], m1[5]);
            m0[6] = __hfma2(wh0, Bq.h[2], m0[6]);  m1[6] = __hfma2(wh1, Bq.h[2], m1[6]);
            m0[7] = __hfma2(wh0, Bq.h[3], m0[7]);  m1[7] = __hfma2(wh1, Bq.h[3], m1[7]);
            m0[8] = __hfma2(wh0, Cq.h[0], m0[8]);  m1[8] = __hfma2(wh1, Cq.h[0], m1[8]);
            m0[9] = __hfma2(wh0, Cq.h[1], m0[9]);  m1[9] = __hfma2(wh1, Cq.h[1], m1[9]);
            m0[10] = __hfma2(wh0, Cq.h[2], m0[10]); m1[10] = __hfma2(wh1, Cq.h[2], m1[10]);
        }
    }

    // Epilogue (log2-domain softmax): softmax update (write Q) or NLL (last iter)
    unsigned int* Qo = Qn + (size_t)b * NP * HW;

    float nll = 0.f;
#pragma unroll
    for (int px = 0; px < 2; ++px) {
        bool ok = px ? v1ok : v0ok;
        if (!ok) continue;
        const __half2* m = px ? m1 : m0;
        float inv = 1.f / ((px ? ws1 : ws0) + 1e-8f);
        int g = g0 + px * W;
        float sv[C];
        float mm = -1e30f;
#pragma unroll
        for (int k = 0; k < NP; ++k) {
            float2 mf = __half22float2(m[k]);
            Hu mgu; mgu.u32 = pfM[px][k];
            float2 mgf = __half22float2(mgu.h);
            Hu uu; uu.u32 = pfU[px][k];
            float2 uf = __half22float2(uu.h);
            int c0 = 2 * k;
            float v0 = fmaf(-L2E, uf.x, fmaf(3.f*L2E, mgf.x, (10.f*L2E) * (mf.x * inv)));
            sv[c0] = v0; mm = fmaxf(mm, v0);
            if (c0 + 1 < C) {
                float v1 = fmaf(-L2E, uf.y, fmaf(3.f*L2E, mgf.y, (10.f*L2E) * (mf.y * inv)));
                sv[c0+1] = v1; mm = fmaxf(mm, v1);
            }
        }
        float s = 0.f;
#pragma unroll
        for (int c = 0; c < C; ++c) { sv[c] = fexp2(sv[c] - mm); s += sv[c]; }
        if (labels) {
            int lab = labels[(size_t)b * HW + g];
            float qsum = 0.f, ql = 1e-8f;
#pragma unroll
            for (int c = 0; c < C; ++c) {
                float qc = sv[c] / s + 1e-8f;
                qsum += qc;
                if (c == lab) ql = qc;
            }
            nll += __logf(qsum) - __logf(ql);
        } else {
            float is = 1.f / s;
#pragma unroll
            for (int k = 0; k < NP; ++k) {
                float a = sv[2*k] * is;
                float bb = (2*k + 1 < C) ? sv[2*k + 1] * is : 0.f;
                Hu xh; xh.h = __floats2half2_rn(a, bb);
                Qo[k*HW + g] = xh.u32;
            }
        }
    }

    if (labels) {
#pragma unroll
        for (int off = 32; off > 0; off >>= 1) nll += __shfl_down(nll, off);
        int lane = tid & 63, wv = tid >> 6;
        if (lane == 0) red[wv] = nll;
        __syncthreads();
        if (tid == 0) part[blk] = red[0] + red[1] + red[2] + red[3] + red[4] + red[5];
    }
}

// ---------------------------------------------------------------------------
__global__ __launch_bounds__(256) void k_final(const float* __restrict__ part,
                                               float* __restrict__ out) {
    int tid = threadIdx.x;
    float s = part[tid] + ((tid < UBLK - 256) ? part[tid + 256] : 0.f);
#pragma unroll
    for (int off = 32; off > 0; off >>= 1) s += __shfl_down(s, off);
    __shared__ float red[4];
    int lane = tid & 63, wv = tid >> 6;
    if (lane == 0) red[wv] = s;
    __syncthreads();
    if (tid == 0) out[0] = (red[0] + red[1] + red[2] + red[3]) / (float)NPIX;
}

// ---------------------------------------------------------------------------
extern "C" void kernel_launch(void* const* d_in, const int* in_sizes, int n_in,
                              void* d_out, int out_size, void* d_ws, size_t ws_size,
                              hipStream_t stream) {
    const float* logits = (const float*)d_in[0];
    const float* images = (const float*)d_in[1];
    const int*   labels = (const int*)d_in[2];
    float* out = (float*)d_out;

    unsigned int* ws = (unsigned int*)d_ws;
    unsigned int* Upk = ws;                     // NB2
    unsigned int* QA  = ws +   (size_t)NB2;     // NB2
    unsigned int* QB  = ws + 2*(size_t)NB2;     // NB2
    unsigned int* Mpk = ws + 3*(size_t)NB2;     // NB2
    uint2*        IQ2 = (uint2*)(ws + 4*(size_t)NB2);    // NPIX uint2
    float*        KT  = (float*)(IQ2 + (size_t)NPIX);    // 64 f32
    float*        PART = KT + 64;                        // 512 f32

    k_ktab<<<1, 64, 0, stream>>>(KT);
    k_prep<<<NPIX/256, 256, 0, stream>>>(images, IQ2);
    k_init<<<NPIX/256, 256, 0, stream>>>(logits, Upk, QA);

    unsigned int* cur = QA;
    unsigned int* oth = QB;
    for (int it = 0; it < 5; ++it) {
        k_gauss<<<B*NP*16, 256, 0, stream>>>(cur, Mpk, KT);
        k_update<<<UBLK, 384, 0, stream>>>(cur, Upk, Mpk, IQ2, oth,
                                           (it == 4) ? labels : nullptr, PART);
        unsigned int* t = cur; cur = oth; oth = t;
    }

    k_final<<<1, 256, 0, stream>>>(PART, out);
    (void)in_sizes; (void)n_in; (void)out_size; (void)ws_size;
}

// Round 11
// 301.364 us; speedup vs baseline: 1.5827x; 1.5827x over previous
//
#include <hip/hip_runtime.h>
#include <hip/hip_fp16.h>
#include <math.h>

// Problem constants
#define B 4
#define C 21
#define NP 11               // f16 channel pairs (ch 2k, 2k+1; pair 10 high = pad)
#define H 256
#define W 256
#define HW (H*W)            // 65536
#define NPIX (B*HW)         // 262144
#define NB2 (B*NP*HW)       // 2883584 packed uint elements

// update tile: 16 wide x 32 tall, 256 threads, 2 rows per thread (R7 geometry)
#define TSX 16
#define TSY 32
#define R 6
#define HXC 28              // halo cols
#define HYR 44              // halo rows
#define NSU (HXC*HYR)       // 1232 records

#define C2F ((float)(1.4426950408889634 / 338.0))   // log2(e)/338
#define L2E 1.4426950408889634f

// weight table: [tile(512)][13 rows][512 px][16B]
#define WT_TILE (13*512)    // uint4 per tile

// Gaussian-fused kernel geometry
#define GOY 64
#define GTR (GOY + 18)      // 82 T rows
#define GTS 17              // padded quad stride

union U4 { uint4 u; __half2 h[4]; };
union Hu { unsigned int u32; __half2 h; };
struct U3 { unsigned int a, b, c; };

#if defined(__has_builtin)
#if __has_builtin(__builtin_amdgcn_udot4)
#define USE_UDOT 1
#endif
#endif

__device__ __forceinline__ float fexp2(float x) {
    float r;
    asm("v_exp_f32 %0, %1" : "=v"(r) : "v"(x));
    return r;
}

typedef __fp16 f16x2 __attribute__((ext_vector_type(2)));
__device__ __forceinline__ __half2 h2bcast(float w) {
    f16x2 t = __builtin_amdgcn_cvt_pkrtz(w, w);   // exact: w is an integer 0..255
    return *(__half2*)&t;
}

// ---------------------------------------------------------------------------
// Gaussian taps: kt[0..18] normalized (sigma=3), kt[19]=w0, kt[20]=1-w0
__global__ void k_ktab(float* __restrict__ kt) {
    if (threadIdx.x == 0) {
        float e[19]; float s = 0.f;
        for (int i = 0; i < 19; ++i) {
            double d = (double)(i - 9);
            e[i] = (float)exp(-(d*d) / 18.0);
            s += e[i];
        }
        for (int i = 0; i < 19; ++i) kt[i] = e[i] / s;
        float k9 = e[9] / s;
        kt[19] = k9 * k9;
        kt[20] = 1.f - k9 * k9;
    }
}

// ---------------------------------------------------------------------------
// Init: U = -log(clip(softmax(logits),1e-5,1)) packed f16; Q0 = softmax(-U) packed f16
__global__ __launch_bounds__(256) void k_init(const float* __restrict__ logits,
                                              unsigned int* __restrict__ Upk,
                                              unsigned int* __restrict__ Qp) {
    int p = blockIdx.x * 256 + threadIdx.x;
    int b = p >> 16, g = p & (HW - 1);
    const float* lp = logits + (size_t)b * C * HW + g;

    float v[C];
    float m = -1e30f;
#pragma unroll
    for (int c = 0; c < C; ++c) { v[c] = lp[c*HW]; m = fmaxf(m, v[c]); }
    float s = 0.f;
#pragma unroll
    for (int c = 0; c < C; ++c) { v[c] = __expf(v[c] - m); s += v[c]; }
    float inv = 1.f / s;

    float u[C];
    float m2 = -1e30f;
#pragma unroll
    for (int c = 0; c < C; ++c) {
        float sm = fminf(fmaxf(v[c] * inv, 1e-5f), 1.f);
        float uu = -__logf(sm);
        u[c] = uu;
        m2 = fmaxf(m2, -uu);
    }
    float s2 = 0.f;
    float q[C];
#pragma unroll
    for (int c = 0; c < C; ++c) { q[c] = __expf(-u[c] - m2); s2 += q[c]; }
    float inv2 = 1.f / s2;

    unsigned int* Ub = Upk + (size_t)b * NP * HW + g;
    unsigned int* Qb = Qp + (size_t)b * NP * HW + g;
#pragma unroll
    for (int k = 0; k < NP; ++k) {
        float ua = u[2*k];
        float ub = (2*k + 1 < C) ? u[2*k + 1] : 0.f;
        Hu xu; xu.h = __floats2half2_rn(ua, ub);
        Ub[k*HW] = xu.u32;
        float qa = q[2*k] * inv2;
        float qb = (2*k + 1 < C) ? q[2*k + 1] * inv2 : 0.f;
        Hu xq; xq.h = __floats2half2_rn(qa, qb);
        Qb[k*HW] = xq.u32;
    }
}

// ---------------------------------------------------------------------------
// Precompute bilateral weights (image-only, iteration-invariant), u8-quantized.
// WT[tile][row 0..12][px 0..511] = uint4 of 13 weights (bytes 13..15 = 0).
__global__ __launch_bounds__(256) void k_wgt(const float* __restrict__ img,
                                             uint4* __restrict__ WT) {
    __shared__ float4 IRGB[NSU];    // quantized rgb halo, 19.7KB

    int blk = blockIdx.x;
    int b = blk >> 7;
    int tile = blk & 127;
    int ty0 = (tile >> 4) * TSY;
    int tx0 = (tile & 15) * TSX;
    int tid = threadIdx.x;

    const float* Ib = img + (size_t)b * 3 * HW;
    for (int s = tid; s < NSU; s += 256) {
        int ly = s / HXC, lx = s - ly * HXC;
        int gy = ty0 + ly - R, gx = tx0 + lx - R;
        bool in = ((unsigned)gy < (unsigned)H) && ((unsigned)gx < (unsigned)W);
        int g = gy * W + gx;
        float r = 0.f, gg = 0.f, bb = 0.f;
        if (in) {
            r  = floorf(fminf(fmaxf(Ib[g]        * 255.f, 0.f), 255.f));
            gg = floorf(fminf(fmaxf(Ib[HW + g]   * 255.f, 0.f), 255.f));
            bb = floorf(fminf(fmaxf(Ib[2*HW + g] * 255.f, 0.f), 255.f));
        }
        IRGB[s] = make_float4(r, gg, bb, 0.f);
    }
    __syncthreads();

    int x = tid & 15, ry = tid >> 4, r0 = 2 * ry;
    int cp0 = (r0 + R) * HXC + x + R;
    float4 c0 = IRGB[cp0];
    float4 c1 = IRGB[cp0 + HXC];
    float DCr = c1.x - c0.x, DCg = c1.y - c0.y, DCb = c1.z - c0.z;
    float DR2 = 2.f*DCr, DG2 = 2.f*DCg, DB2 = 2.f*DCb;
    float DC2 = DCr*DCr + DCg*DCg + DCb*DCb;

    uint4* base = WT + (size_t)blk * WT_TILE;
    int px0 = r0 * 16 + x;

    for (int dyy = 0; dyy < 14; ++dyy) {
        int t0 = dyy - 6, t1 = dyy - 7;
        float a0 = -(float)(t0*t0) * C2F;
        float a1 = -(float)(t1*t1) * C2F;
        unsigned int wa0[4] = {0u,0u,0u,0u}, wa1[4] = {0u,0u,0u,0u};
        int rowb = (r0 + dyy) * HXC + x;
#pragma unroll
        for (int dx = 0; dx < 13; ++dx) {
            float4 n = IRGB[rowb + dx];
            float d0r = c0.x - n.x, d0g = c0.y - n.y, d0b = c0.z - n.z;
            float ss0 = fmaf(d0r, d0r, fmaf(d0g, d0g, d0b * d0b));
            float ss1 = fmaf(DR2, d0r, fmaf(DG2, d0g, fmaf(DB2, d0b, ss0 + DC2)));
            float cc = -(float)((dx - 6) * (dx - 6)) * C2F;
            float w0 = fexp2(fmaf(ss0, -C2F, a0 + cc));
            float w1 = fexp2(fmaf(ss1, -C2F, a1 + cc));
            if (dyy == 6 && dx == 6) w0 = 0.f;   // exact center exclusion
            if (dyy == 7 && dx == 6) w1 = 0.f;
            unsigned int u0 = (unsigned int)fmaf(w0, 255.f, 0.5f);
            unsigned int u1 = (unsigned int)fmaf(w1, 255.f, 0.5f);
            wa0[dx >> 2] |= u0 << (8 * (dx & 3));
            wa1[dx >> 2] |= u1 << (8 * (dx & 3));
        }
        if (dyy <= 12) base[dyy*512 + px0]          = make_uint4(wa0[0], wa0[1], wa0[2], wa0[3]);
        if (dyy >= 1)  base[(dyy-1)*512 + px0 + 16] = make_uint4(wa1[0], wa1[1], wa1[2], wa1[3]);
    }
}

// ---------------------------------------------------------------------------
// Fused separable Gaussian + message: MG = (conv - w0*Q)*(1/(1-w0)).
__global__ __launch_bounds__(256) void k_gauss(const unsigned int* __restrict__ Q,
                                               unsigned int* __restrict__ MG,
                                               const float* __restrict__ kt) {
    __shared__ uint4 T[GTR * GTS];
    __shared__ float kf[21];

    int tid = threadIdx.x;
    if (tid < 21) kf[tid] = kt[tid];
    __syncthreads();

    __half2 kh[19];
#pragma unroll
    for (int j = 0; j < 19; ++j) kh[j] = __float2half2_rn(kf[j]);

    int blk = blockIdx.x;
    int pl  = blk >> 4;
    int sub = blk & 15;
    int y0 = (sub >> 2) * GOY;
    int x0 = (sub & 3) * 64;
    const unsigned int* base = Q + (size_t)pl * HW;

    for (int s = tid; s < GTR * 16; s += 256) {
        int row = s >> 4;
        int q   = s & 15;
        int yy = y0 + row - 9;
        U4 o;
        o.u = make_uint4(0u, 0u, 0u, 0u);
        if ((unsigned)yy < (unsigned)H) {
            int xb = x0 + q * 4;
            const unsigned int* rp = base + yy * W;
            U4 ch[7];
#pragma unroll
            for (int c2 = 0; c2 < 7; ++c2) {
                int xq = xb - 12 + c2 * 4;
                if ((unsigned)xq < (unsigned)W) ch[c2].u = *(const uint4*)(rp + xq);
                else ch[c2].u = make_uint4(0u, 0u, 0u, 0u);
            }
            const __half2* v = (const __half2*)ch;
#pragma unroll
            for (int i = 0; i < 4; ++i) {
                __half2 acc = __float2half2_rn(0.f);
#pragma unroll
                for (int j = 0; j < 19; ++j) acc = __hfma2(kh[j], v[i + 3 + j], acc);
                o.h[i] = acc;
            }
        }
        T[row * GTS + q] = o.u;
    }
    __syncthreads();

    __half2 nw0  = __float2half2_rn(-kf[19]);
    __half2 inv1 = __float2half2_rn(1.f / kf[20]);
    int q  = tid & 15;
    int rg = tid >> 4;
    int r0 = rg * 4;

    __half2 acc[4][4];
#pragma unroll
    for (int i = 0; i < 4; ++i)
#pragma unroll
        for (int qd = 0; qd < 4; ++qd) acc[i][qd] = __float2half2_rn(0.f);

#pragma unroll
    for (int j = 0; j < 22; ++j) {
        U4 f; f.u = T[(r0 + j) * GTS + q];
#pragma unroll
        for (int i = 0; i < 4; ++i) {
            int tap = j - i;
            if (tap >= 0 && tap <= 18) {
#pragma unroll
                for (int qd = 0; qd < 4; ++qd)
                    acc[i][qd] = __hfma2(kh[tap], f.h[qd], acc[i][qd]);
            }
        }
    }

#pragma unroll
    for (int i = 0; i < 4; ++i) {
        size_t e = (size_t)pl * HW + (y0 + r0 + i) * W + x0 + q * 4;
        U4 qq; qq.u = *(const uint4*)(Q + e);
        U4 o;
#pragma unroll
        for (int qd = 0; qd < 4; ++qd)
            o.h[qd] = __hmul2(__hfma2(nw0, qq.h[qd], acc[i][qd]), inv1);
        *(uint4*)(MG + e) = o.u;
    }
}

// ---------------------------------------------------------------------------
// Bilateral message (precomputed u8 weights) + mean-field update, 2 px/thread.
// Per tap: 3 LDS reads + byte->f32 cvt + pkrtz + 22 hfma2. No color math.
__global__ __launch_bounds__(256) void k_update(const unsigned int* __restrict__ Q,
                                                const unsigned int* __restrict__ Upk,
                                                const unsigned int* __restrict__ MG,
                                                const uint4* __restrict__ WT,
                                                unsigned int* __restrict__ Qn,
                                                const int* __restrict__ labels,
                                                float* __restrict__ part) {
    __shared__ uint4 LA[NSU];   // ch 0..7   (19712 B)
    __shared__ uint4 LB[NSU];   // ch 8..15  (19712 B)
    __shared__ U3    LCC[NSU];  // ch 16..20 + pad (14784 B)  -> total 54.2 KB
    __shared__ float red[4];

    int blk = blockIdx.x;
    int b = blk >> 7;
    int tile = blk & 127;
    int ty0 = (tile >> 4) * TSY;
    int tx0 = (tile & 15) * TSX;
    int tid = threadIdx.x;

    const unsigned int* Qb = Q + (size_t)b * NP * HW;

    for (int s = tid; s < NSU; s += 256) {
        int ly = s / HXC;
        int lx = s - ly * HXC;
        int gy = ty0 + ly - R;
        int gx = tx0 + lx - R;
        bool in = ((unsigned)gy < (unsigned)H) && ((unsigned)gx < (unsigned)W);
        int g = gy * W + gx;
        unsigned int u[NP];
#pragma unroll
        for (int k = 0; k < NP; ++k) u[k] = in ? Qb[k*HW + g] : 0u;
        LA[s] = make_uint4(u[0], u[1], u[2], u[3]);
        LB[s] = make_uint4(u[4], u[5], u[6], u[7]);
        U3 t; t.a = u[8]; t.b = u[9]; t.c = u[10];
        LCC[s] = t;
    }
    __syncthreads();

    int x = tid & 15;
    int ry = tid >> 4;                // 0..15 -> rows 2ry, 2ry+1
    int r0 = 2 * ry;
    int g0 = (ty0 + r0) * W + (tx0 + x);
    int px0 = r0 * 16 + x;

    // epilogue prefetch
    const unsigned int* Ub = Upk + (size_t)b * NP * HW;
    const unsigned int* Mb = MG + (size_t)b * NP * HW;
    unsigned int pfU[2][NP], pfM[2][NP];
#pragma unroll
    for (int k = 0; k < NP; ++k) {
        pfU[0][k] = Ub[k*HW + g0];       pfM[0][k] = Mb[k*HW + g0];
        pfU[1][k] = Ub[k*HW + g0 + W];   pfM[1][k] = Mb[k*HW + g0 + W];
    }

    const uint4* wbase = WT + (size_t)blk * WT_TILE;

    __half2 m0[NP], m1[NP];
#pragma unroll
    for (int k = 0; k < NP; ++k) { m0[k] = __float2half2_rn(0.f); m1[k] = m0[k]; }
#ifdef USE_UDOT
    unsigned int ws0i = 0u, ws1i = 0u;
#else
    float ws0f = 0.f, ws1f = 0.f;
#endif

    for (int dyy = 0; dyy < 14; ++dyy) {
        uint4 w0r = (dyy <= 12) ? wbase[dyy*512 + px0]
                                : make_uint4(0u, 0u, 0u, 0u);
        uint4 w1r = (dyy >= 1)  ? wbase[(dyy-1)*512 + px0 + 16]
                                : make_uint4(0u, 0u, 0u, 0u);
#ifdef USE_UDOT
        ws0i = __builtin_amdgcn_udot4(w0r.x, 0x01010101u, ws0i, false);
        ws0i = __builtin_amdgcn_udot4(w0r.y, 0x01010101u, ws0i, false);
        ws0i = __builtin_amdgcn_udot4(w0r.z, 0x01010101u, ws0i, false);
        ws0i = __builtin_amdgcn_udot4(w0r.w, 0x01010101u, ws0i, false);
        ws1i = __builtin_amdgcn_udot4(w1r.x, 0x01010101u, ws1i, false);
        ws1i = __builtin_amdgcn_udot4(w1r.y, 0x01010101u, ws1i, false);
        ws1i = __builtin_amdgcn_udot4(w1r.z, 0x01010101u, ws1i, false);
        ws1i = __builtin_amdgcn_udot4(w1r.w, 0x01010101u, ws1i, false);
#endif
        int rowb = (r0 + dyy) * HXC + x;
#pragma unroll
        for (int dx = 0; dx < 13; ++dx) {
            int p = rowb + dx;
            U4 A, Bq;
            A.u  = LA[p];
            Bq.u = LB[p];
            U3 cx = LCC[p];
            unsigned int q0 = (dx < 4) ? w0r.x : (dx < 8) ? w0r.y : (dx < 12) ? w0r.z : w0r.w;
            unsigned int q1 = (dx < 4) ? w1r.x : (dx < 8) ? w1r.y : (dx < 12) ? w1r.z : w1r.w;
            float w0 = (float)((q0 >> (8 * (dx & 3))) & 0xffu);   // v_cvt_f32_ubyteN
            float w1 = (float)((q1 >> (8 * (dx & 3))) & 0xffu);
#ifndef USE_UDOT
            ws0f += w0; ws1f += w1;
#endif
            __half2 wh0 = h2bcast(w0);
            __half2 wh1 = h2bcast(w1);
            Hu ca; ca.u32 = cx.a;  Hu cb; cb.u32 = cx.b;  Hu cc; cc.u32 = cx.c;
            m0[0] = __hfma2(wh0, A.h[0], m0[0]);   m1[0] = __hfma2(wh1, A.h[0], m1[0]);
            m0[1] = __hfma2(wh0, A.h[1], m0[1]);   m1[1] = __hfma2(wh1, A.h[1], m1[1]);
            m0[2] = __hfma2(wh0, A.h[2], m0[2]);   m1[2] = __hfma2(wh1, A.h[2], m1[2]);
            m0[3] = __hfma2(wh0, A.h[3], m0[3]);   m1[3] = __hfma2(wh1, A.h[3], m1[3]);
            m0[4] = __hfma2(wh0, Bq.h[0], m0[4]);  m1[4] = __hfma2(wh1, Bq.h[0], m1[4]);
            m0[5] = __hfma2(wh0, Bq.h[1], m0[5]);  m1[5] = __hfma2(wh1, Bq.h[1], m1[5]);
            m0[6] = __hfma2(wh0, Bq.h[2], m0[6]);  m1[6] = __hfma2(wh1, Bq.h[2], m1[6]);
            m0[7] = __hfma2(wh0, Bq.h[3], m0[7]);  m1[7] = __hfma2(wh1, Bq.h[3], m1[7]);
            m0[8] = __hfma2(wh0, ca.h, m0[8]);     m1[8] = __hfma2(wh1, ca.h, m1[8]);
            m0[9] = __hfma2(wh0, cb.h, m0[9]);     m1[9] = __hfma2(wh1, cb.h, m1[9]);
            m0[10] = __hfma2(wh0, cc.h, m0[10]);   m1[10] = __hfma2(wh1, cc.h, m1[10]);
        }
    }

#ifdef USE_UDOT
    float ws0 = (float)ws0i, ws1 = (float)ws1i;
#else
    float ws0 = ws0f, ws1 = ws1f;
#endif

    // Epilogue (log2-domain softmax). Messages and wsum are both x255-scaled;
    // msg/wsum is invariant; 1e-8 rescales to 2.55e-6.
    unsigned int* Qo = Qn + (size_t)b * NP * HW;

    float nll = 0.f;
#pragma unroll
    for (int px = 0; px < 2; ++px) {
        const __half2* m = px ? m1 : m0;
        float inv = 1.f / ((px ? ws1 : ws0) + 2.55e-6f);
        int g = g0 + px * W;
        float sv[C];
        float mm = -1e30f;
#pragma unroll
        for (int k = 0; k < NP; ++k) {
            float2 mf = __half22float2(m[k]);
            Hu mgu; mgu.u32 = pfM[px][k];
            float2 mgf = __half22float2(mgu.h);
            Hu uu; uu.u32 = pfU[px][k];
            float2 uf = __half22float2(uu.h);
            int c0 = 2 * k;
            float v0 = fmaf(-L2E, uf.x, fmaf(3.f*L2E, mgf.x, (10.f*L2E) * (mf.x * inv)));
            sv[c0] = v0; mm = fmaxf(mm, v0);
            if (c0 + 1 < C) {
                float v1 = fmaf(-L2E, uf.y, fmaf(3.f*L2E, mgf.y, (10.f*L2E) * (mf.y * inv)));
                sv[c0+1] = v1; mm = fmaxf(mm, v1);
            }
        }
        float s = 0.f;
#pragma unroll
        for (int c = 0; c < C; ++c) { sv[c] = fexp2(sv[c] - mm); s += sv[c]; }
        if (labels) {
            int lab = labels[(size_t)b * HW + g];
            float qsum = 0.f, ql = 1e-8f;
#pragma unroll
            for (int c = 0; c < C; ++c) {
                float qc = sv[c] / s + 1e-8f;
                qsum += qc;
                if (c == lab) ql = qc;
            }
            nll += __logf(qsum) - __logf(ql);
        } else {
            float is = 1.f / s;
#pragma unroll
            for (int k = 0; k < NP; ++k) {
                float a = sv[2*k] * is;
                float bb = (2*k + 1 < C) ? sv[2*k + 1] * is : 0.f;
                Hu xh; xh.h = __floats2half2_rn(a, bb);
                Qo[k*HW + g] = xh.u32;
            }
        }
    }

    if (labels) {
#pragma unroll
        for (int off = 32; off > 0; off >>= 1) nll += __shfl_down(nll, off);
        int lane = tid & 63, wv = tid >> 6;
        if (lane == 0) red[wv] = nll;
        __syncthreads();
        if (tid == 0) part[blk] = red[0] + red[1] + red[2] + red[3];
    }
}

// ---------------------------------------------------------------------------
__global__ __launch_bounds__(256) void k_final(const float* __restrict__ part,
                                               float* __restrict__ out) {
    int tid = threadIdx.x;
    float s = part[tid] + part[tid + 256];
#pragma unroll
    for (int off = 32; off > 0; off >>= 1) s += __shfl_down(s, off);
    __shared__ float red[4];
    int lane = tid & 63, wv = tid >> 6;
    if (lane == 0) red[wv] = s;
    __syncthreads();
    if (tid == 0) out[0] = (red[0] + red[1] + red[2] + red[3]) / (float)NPIX;
}

// ---------------------------------------------------------------------------
extern "C" void kernel_launch(void* const* d_in, const int* in_sizes, int n_in,
                              void* d_out, int out_size, void* d_ws, size_t ws_size,
                              hipStream_t stream) {
    const float* logits = (const float*)d_in[0];
    const float* images = (const float*)d_in[1];
    const int*   labels = (const int*)d_in[2];
    float* out = (float*)d_out;

    unsigned int* ws = (unsigned int*)d_ws;
    unsigned int* Upk = ws;                     // NB2
    unsigned int* QA  = ws +   (size_t)NB2;     // NB2
    unsigned int* QB  = ws + 2*(size_t)NB2;     // NB2
    unsigned int* Mpk = ws + 3*(size_t)NB2;     // NB2
    uint4*        WT  = (uint4*)(ws + 4*(size_t)NB2);        // 512*13*512 uint4 = 54.5MB
    float*        KT  = (float*)(WT + (size_t)512*WT_TILE);  // 64 f32
    float*        PART = KT + 64;                            // 512 f32

    k_ktab<<<1, 64, 0, stream>>>(KT);
    k_init<<<NPIX/256, 256, 0, stream>>>(logits, Upk, QA);
    k_wgt<<<B*128, 256, 0, stream>>>(images, WT);

    unsigned int* cur = QA;
    unsigned int* oth = QB;
    for (int it = 0; it < 5; ++it) {
        k_gauss<<<B*NP*16, 256, 0, stream>>>(cur, Mpk, KT);
        k_update<<<B*128, 256, 0, stream>>>(cur, Upk, Mpk, WT, oth,
                                            (it == 4) ? labels : nullptr, PART);
        unsigned int* t = cur; cur = oth; oth = t;
    }

    k_final<<<1, 256, 0, stream>>>(PART, out);
    (void)in_sizes; (void)n_in; (void)out_size; (void)ws_size;
}

// Round 12
// 293.414 us; speedup vs baseline: 1.6256x; 1.0271x over previous
//
#include <hip/hip_runtime.h>
#include <hip/hip_fp16.h>
#include <math.h>

// Problem constants
#define B 4
#define C 21
#define NP 11               // f16 channel pairs (ch 2k, 2k+1; pair 10 high = pad)
#define H 256
#define W 256
#define HW (H*W)            // 65536
#define NPIX (B*HW)         // 262144
#define NB2 (B*NP*HW)       // 2883584 packed uint elements

// update tile: 16 wide x 32 tall, 256 threads, 2 rows per thread
#define TSX 16
#define TSY 32
#define R 6
#define HXC 28              // halo cols
#define HYR 44              // halo rows
#define NSU (HXC*HYR)       // 1232 records

#define C2F ((float)(1.4426950408889634 / 338.0))   // log2(e)/338
#define L2E 1.4426950408889634f

// weight table: [tile(512)][15 rows][512 px][16B]; rows 13,14 zeroed (pipeline pad)
#define WT_ROWS 15
#define WT_TILE (WT_ROWS*512)    // uint4 per tile

// Gaussian-fused kernel geometry
#define GOY 64
#define GTR (GOY + 18)      // 82 T rows
#define GTS 17              // padded quad stride

union U4 { uint4 u; __half2 h[4]; };
union Hu { unsigned int u32; __half2 h; };
struct U3 { unsigned int a, b, c; };

#if defined(__has_builtin)
#if __has_builtin(__builtin_amdgcn_udot4)
#define USE_UDOT 1
#endif
#endif

__device__ __forceinline__ float fexp2(float x) {
    float r;
    asm("v_exp_f32 %0, %1" : "=v"(r) : "v"(x));
    return r;
}

typedef __fp16 f16x2 __attribute__((ext_vector_type(2)));
__device__ __forceinline__ __half2 h2bcast(float w) {
    f16x2 t = __builtin_amdgcn_cvt_pkrtz(w, w);   // exact: w is an integer 0..255
    return *(__half2*)&t;
}

// ---------------------------------------------------------------------------
// Init: U = -log(clip(softmax(logits),1e-5,1)) packed f16; Q0 = softmax(-U).
// Block 0 / thread 0 also fills the Gaussian tap table (used by k_gauss later).
__global__ __launch_bounds__(256) void k_init(const float* __restrict__ logits,
                                              unsigned int* __restrict__ Upk,
                                              unsigned int* __restrict__ Qp,
                                              float* __restrict__ kt) {
    int p = blockIdx.x * 256 + threadIdx.x;
    if (p == 0) {
        float e[19]; float s0 = 0.f;
        for (int i = 0; i < 19; ++i) {
            double d = (double)(i - 9);
            e[i] = (float)exp(-(d*d) / 18.0);
            s0 += e[i];
        }
        for (int i = 0; i < 19; ++i) kt[i] = e[i] / s0;
        float k9 = e[9] / s0;
        kt[19] = k9 * k9;
        kt[20] = 1.f - k9 * k9;
    }
    int b = p >> 16, g = p & (HW - 1);
    const float* lp = logits + (size_t)b * C * HW + g;

    float v[C];
    float m = -1e30f;
#pragma unroll
    for (int c = 0; c < C; ++c) { v[c] = lp[c*HW]; m = fmaxf(m, v[c]); }
    float s = 0.f;
#pragma unroll
    for (int c = 0; c < C; ++c) { v[c] = __expf(v[c] - m); s += v[c]; }
    float inv = 1.f / s;

    float u[C];
    float m2 = -1e30f;
#pragma unroll
    for (int c = 0; c < C; ++c) {
        float sm = fminf(fmaxf(v[c] * inv, 1e-5f), 1.f);
        float uu = -__logf(sm);
        u[c] = uu;
        m2 = fmaxf(m2, -uu);
    }
    float s2 = 0.f;
    float q[C];
#pragma unroll
    for (int c = 0; c < C; ++c) { q[c] = __expf(-u[c] - m2); s2 += q[c]; }
    float inv2 = 1.f / s2;

    unsigned int* Ub = Upk + (size_t)b * NP * HW + g;
    unsigned int* Qb = Qp + (size_t)b * NP * HW + g;
#pragma unroll
    for (int k = 0; k < NP; ++k) {
        float ua = u[2*k];
        float ub = (2*k + 1 < C) ? u[2*k + 1] : 0.f;
        Hu xu; xu.h = __floats2half2_rn(ua, ub);
        Ub[k*HW] = xu.u32;
        float qa = q[2*k] * inv2;
        float qb = (2*k + 1 < C) ? q[2*k + 1] * inv2 : 0.f;
        Hu xq; xq.h = __floats2half2_rn(qa, qb);
        Qb[k*HW] = xq.u32;
    }
}

// ---------------------------------------------------------------------------
// Precompute bilateral weights (image-only, iteration-invariant), u8-quantized.
// WT[tile][row 0..12][px 0..511] = uint4 of 13 weights; rows 13,14 zeroed.
__global__ __launch_bounds__(256) void k_wgt(const float* __restrict__ img,
                                             uint4* __restrict__ WT) {
    __shared__ float4 IRGB[NSU];    // quantized rgb halo, 19.7KB

    int blk = blockIdx.x;
    int b = blk >> 7;
    int tile = blk & 127;
    int ty0 = (tile >> 4) * TSY;
    int tx0 = (tile & 15) * TSX;
    int tid = threadIdx.x;

    const float* Ib = img + (size_t)b * 3 * HW;
    for (int s = tid; s < NSU; s += 256) {
        int ly = s / HXC, lx = s - ly * HXC;
        int gy = ty0 + ly - R, gx = tx0 + lx - R;
        bool in = ((unsigned)gy < (unsigned)H) && ((unsigned)gx < (unsigned)W);
        int g = gy * W + gx;
        float r = 0.f, gg = 0.f, bb = 0.f;
        if (in) {
            r  = floorf(fminf(fmaxf(Ib[g]        * 255.f, 0.f), 255.f));
            gg = floorf(fminf(fmaxf(Ib[HW + g]   * 255.f, 0.f), 255.f));
            bb = floorf(fminf(fmaxf(Ib[2*HW + g] * 255.f, 0.f), 255.f));
        }
        IRGB[s] = make_float4(r, gg, bb, 0.f);
    }
    __syncthreads();

    int x = tid & 15, ry = tid >> 4, r0 = 2 * ry;
    int cp0 = (r0 + R) * HXC + x + R;
    float4 c0 = IRGB[cp0];
    float4 c1 = IRGB[cp0 + HXC];
    float DCr = c1.x - c0.x, DCg = c1.y - c0.y, DCb = c1.z - c0.z;
    float DR2 = 2.f*DCr, DG2 = 2.f*DCg, DB2 = 2.f*DCb;
    float DC2 = DCr*DCr + DCg*DCg + DCb*DCb;

    uint4* base = WT + (size_t)blk * WT_TILE;
    int px0 = r0 * 16 + x;

    for (int dyy = 0; dyy < 14; ++dyy) {
        int t0 = dyy - 6, t1 = dyy - 7;
        float a0 = -(float)(t0*t0) * C2F;
        float a1 = -(float)(t1*t1) * C2F;
        unsigned int wa0[4] = {0u,0u,0u,0u}, wa1[4] = {0u,0u,0u,0u};
        int rowb = (r0 + dyy) * HXC + x;
#pragma unroll
        for (int dx = 0; dx < 13; ++dx) {
            float4 n = IRGB[rowb + dx];
            float d0r = c0.x - n.x, d0g = c0.y - n.y, d0b = c0.z - n.z;
            float ss0 = fmaf(d0r, d0r, fmaf(d0g, d0g, d0b * d0b));
            float ss1 = fmaf(DR2, d0r, fmaf(DG2, d0g, fmaf(DB2, d0b, ss0 + DC2)));
            float cc = -(float)((dx - 6) * (dx - 6)) * C2F;
            float w0 = fexp2(fmaf(ss0, -C2F, a0 + cc));
            float w1 = fexp2(fmaf(ss1, -C2F, a1 + cc));
            if (dyy == 6 && dx == 6) w0 = 0.f;   // exact center exclusion
            if (dyy == 7 && dx == 6) w1 = 0.f;
            unsigned int u0 = (unsigned int)fmaf(w0, 255.f, 0.5f);
            unsigned int u1 = (unsigned int)fmaf(w1, 255.f, 0.5f);
            wa0[dx >> 2] |= u0 << (8 * (dx & 3));
            wa1[dx >> 2] |= u1 << (8 * (dx & 3));
        }
        if (dyy <= 12) base[dyy*512 + px0]          = make_uint4(wa0[0], wa0[1], wa0[2], wa0[3]);
        if (dyy >= 1)  base[(dyy-1)*512 + px0 + 16] = make_uint4(wa1[0], wa1[1], wa1[2], wa1[3]);
    }
    // zero pipeline-pad rows 13,14 (each thread covers px0 and px0+16)
    uint4 z = make_uint4(0u, 0u, 0u, 0u);
    base[13*512 + px0] = z;  base[13*512 + px0 + 16] = z;
    base[14*512 + px0] = z;  base[14*512 + px0 + 16] = z;
}

// ---------------------------------------------------------------------------
// Fused separable Gaussian + message: MG = (conv - w0*Q)*(1/(1-w0)).
__global__ __launch_bounds__(256) void k_gauss(const unsigned int* __restrict__ Q,
                                               unsigned int* __restrict__ MG,
                                               const float* __restrict__ kt) {
    __shared__ uint4 T[GTR * GTS];
    __shared__ float kf[21];

    int tid = threadIdx.x;
    if (tid < 21) kf[tid] = kt[tid];
    __syncthreads();

    __half2 kh[19];
#pragma unroll
    for (int j = 0; j < 19; ++j) kh[j] = __float2half2_rn(kf[j]);

    int blk = blockIdx.x;
    int pl  = blk >> 4;
    int sub = blk & 15;
    int y0 = (sub >> 2) * GOY;
    int x0 = (sub & 3) * 64;
    const unsigned int* base = Q + (size_t)pl * HW;

    for (int s = tid; s < GTR * 16; s += 256) {
        int row = s >> 4;
        int q   = s & 15;
        int yy = y0 + row - 9;
        U4 o;
        o.u = make_uint4(0u, 0u, 0u, 0u);
        if ((unsigned)yy < (unsigned)H) {
            int xb = x0 + q * 4;
            const unsigned int* rp = base + yy * W;
            U4 ch[7];
#pragma unroll
            for (int c2 = 0; c2 < 7; ++c2) {
                int xq = xb - 12 + c2 * 4;
                if ((unsigned)xq < (unsigned)W) ch[c2].u = *(const uint4*)(rp + xq);
                else ch[c2].u = make_uint4(0u, 0u, 0u, 0u);
            }
            const __half2* v = (const __half2*)ch;
#pragma unroll
            for (int i = 0; i < 4; ++i) {
                __half2 acc = __float2half2_rn(0.f);
#pragma unroll
                for (int j = 0; j < 19; ++j) acc = __hfma2(kh[j], v[i + 3 + j], acc);
                o.h[i] = acc;
            }
        }
        T[row * GTS + q] = o.u;
    }
    __syncthreads();

    __half2 nw0  = __float2half2_rn(-kf[19]);
    __half2 inv1 = __float2half2_rn(1.f / kf[20]);
    int q  = tid & 15;
    int rg = tid >> 4;
    int r0 = rg * 4;

    __half2 acc[4][4];
#pragma unroll
    for (int i = 0; i < 4; ++i)
#pragma unroll
        for (int qd = 0; qd < 4; ++qd) acc[i][qd] = __float2half2_rn(0.f);

#pragma unroll
    for (int j = 0; j < 22; ++j) {
        U4 f; f.u = T[(r0 + j) * GTS + q];
#pragma unroll
        for (int i = 0; i < 4; ++i) {
            int tap = j - i;
            if (tap >= 0 && tap <= 18) {
#pragma unroll
                for (int qd = 0; qd < 4; ++qd)
                    acc[i][qd] = __hfma2(kh[tap], f.h[qd], acc[i][qd]);
            }
        }
    }

#pragma unroll
    for (int i = 0; i < 4; ++i) {
        size_t e = (size_t)pl * HW + (y0 + r0 + i) * W + x0 + q * 4;
        U4 qq; qq.u = *(const uint4*)(Q + e);
        U4 o;
#pragma unroll
        for (int qd = 0; qd < 4; ++qd)
            o.h[qd] = __hmul2(__hfma2(nw0, qq.h[qd], acc[i][qd]), inv1);
        *(uint4*)(MG + e) = o.u;
    }
}

// ---------------------------------------------------------------------------
// Bilateral message (precomputed u8 weights, software-pipelined WT loads)
// + mean-field update, 2 px/thread.
__global__ __launch_bounds__(256) void k_update(const unsigned int* __restrict__ Q,
                                                const unsigned int* __restrict__ Upk,
                                                const unsigned int* __restrict__ MG,
                                                const uint4* __restrict__ WT,
                                                unsigned int* __restrict__ Qn,
                                                const int* __restrict__ labels,
                                                float* __restrict__ part) {
    __shared__ uint4 LA[NSU];   // ch 0..7   (19712 B)
    __shared__ uint4 LB[NSU];   // ch 8..15  (19712 B)
    __shared__ U3    LCC[NSU];  // ch 16..20 + pad (14784 B)  -> total 54.2 KB
    __shared__ float red[4];

    int blk = blockIdx.x;
    int b = blk >> 7;
    int tile = blk & 127;
    int ty0 = (tile >> 4) * TSY;
    int tx0 = (tile & 15) * TSX;
    int tid = threadIdx.x;

    const unsigned int* Qb = Q + (size_t)b * NP * HW;

    // explicit 5-step staging (compile-time trip count -> batched loads)
#pragma unroll
    for (int i = 0; i < 5; ++i) {
        int s = tid + i * 256;
        if (s < NSU) {
            int ly = s / HXC;
            int lx = s - ly * HXC;
            int gy = ty0 + ly - R;
            int gx = tx0 + lx - R;
            bool in = ((unsigned)gy < (unsigned)H) && ((unsigned)gx < (unsigned)W);
            int g = gy * W + gx;
            unsigned int u[NP];
#pragma unroll
            for (int k = 0; k < NP; ++k) u[k] = in ? Qb[k*HW + g] : 0u;
            LA[s] = make_uint4(u[0], u[1], u[2], u[3]);
            LB[s] = make_uint4(u[4], u[5], u[6], u[7]);
            U3 t; t.a = u[8]; t.b = u[9]; t.c = u[10];
            LCC[s] = t;
        }
    }
    __syncthreads();

    int x = tid & 15;
    int ry = tid >> 4;                // 0..15 -> rows 2ry, 2ry+1
    int r0 = 2 * ry;
    int g0 = (ty0 + r0) * W + (tx0 + x);
    int px0 = r0 * 16 + x;

    // epilogue prefetch
    const unsigned int* Ub = Upk + (size_t)b * NP * HW;
    const unsigned int* Mb = MG + (size_t)b * NP * HW;
    unsigned int pfU[2][NP], pfM[2][NP];
#pragma unroll
    for (int k = 0; k < NP; ++k) {
        pfU[0][k] = Ub[k*HW + g0];       pfM[0][k] = Mb[k*HW + g0];
        pfU[1][k] = Ub[k*HW + g0 + W];   pfM[1][k] = Mb[k*HW + g0 + W];
    }

    const uint4* wbase = WT + (size_t)blk * WT_TILE;

    __half2 m0[NP], m1[NP];
#pragma unroll
    for (int k = 0; k < NP; ++k) { m0[k] = __float2half2_rn(0.f); m1[k] = m0[k]; }
#ifdef USE_UDOT
    unsigned int ws0i = 0u, ws1i = 0u;
#else
    float ws0f = 0.f, ws1f = 0.f;
#endif

    // software-pipelined weight rows: prefetch dyy+1 while computing dyy
    uint4 w0r = wbase[px0];                 // w0 row 0
    uint4 w1r = make_uint4(0u, 0u, 0u, 0u); // w1 row -1 = zero

    for (int dyy = 0; dyy < 14; ++dyy) {
        uint4 nw0 = wbase[(dyy + 1) * 512 + px0];        // rows 1..14 (13,14 zero)
        uint4 nw1 = wbase[dyy * 512 + px0 + 16];         // w1 rows 0..13 (13 zero)
#ifdef USE_UDOT
        ws0i = __builtin_amdgcn_udot4(w0r.x, 0x01010101u, ws0i, false);
        ws0i = __builtin_amdgcn_udot4(w0r.y, 0x01010101u, ws0i, false);
        ws0i = __builtin_amdgcn_udot4(w0r.z, 0x01010101u, ws0i, false);
        ws0i = __builtin_amdgcn_udot4(w0r.w, 0x01010101u, ws0i, false);
        ws1i = __builtin_amdgcn_udot4(w1r.x, 0x01010101u, ws1i, false);
        ws1i = __builtin_amdgcn_udot4(w1r.y, 0x01010101u, ws1i, false);
        ws1i = __builtin_amdgcn_udot4(w1r.z, 0x01010101u, ws1i, false);
        ws1i = __builtin_amdgcn_udot4(w1r.w, 0x01010101u, ws1i, false);
#endif
        int rowb = (r0 + dyy) * HXC + x;
#pragma unroll
        for (int dx = 0; dx < 13; ++dx) {
            int p = rowb + dx;
            U4 A, Bq;
            A.u  = LA[p];
            Bq.u = LB[p];
            U3 cx = LCC[p];
            unsigned int q0 = (dx < 4) ? w0r.x : (dx < 8) ? w0r.y : (dx < 12) ? w0r.z : w0r.w;
            unsigned int q1 = (dx < 4) ? w1r.x : (dx < 8) ? w1r.y : (dx < 12) ? w1r.z : w1r.w;
            float w0 = (float)((q0 >> (8 * (dx & 3))) & 0xffu);   // v_cvt_f32_ubyteN
            float w1 = (float)((q1 >> (8 * (dx & 3))) & 0xffu);
#ifndef USE_UDOT
            ws0f += w0; ws1f += w1;
#endif
            __half2 wh0 = h2bcast(w0);
            __half2 wh1 = h2bcast(w1);
            Hu ca; ca.u32 = cx.a;  Hu cb; cb.u32 = cx.b;  Hu cc; cc.u32 = cx.c;
            m0[0] = __hfma2(wh0, A.h[0], m0[0]);   m1[0] = __hfma2(wh1, A.h[0], m1[0]);
            m0[1] = __hfma2(wh0, A.h[1], m0[1]);   m1[1] = __hfma2(wh1, A.h[1], m1[1]);
            m0[2] = __hfma2(wh0, A.h[2], m0[2]);   m1[2] = __hfma2(wh1, A.h[2], m1[2]);
            m0[3] = __hfma2(wh0, A.h[3], m0[3]);   m1[3] = __hfma2(wh1, A.h[3], m1[3]);
            m0[4] = __hfma2(wh0, Bq.h[0], m0[4]);  m1[4] = __hfma2(wh1, Bq.h[0], m1[4]);
            m0[5] = __hfma2(wh0, Bq.h[1], m0[5]);  m1[5] = __hfma2(wh1, Bq.h[1], m1[5]);
            m0[6] = __hfma2(wh0, Bq.h[2], m0[6]);  m1[6] = __hfma2(wh1, Bq.h[2], m1[6]);
            m0[7] = __hfma2(wh0, Bq.h[3], m0[7]);  m1[7] = __hfma2(wh1, Bq.h[3], m1[7]);
            m0[8] = __hfma2(wh0, ca.h, m0[8]);     m1[8] = __hfma2(wh1, ca.h, m1[8]);
            m0[9] = __hfma2(wh0, cb.h, m0[9]);     m1[9] = __hfma2(wh1, cb.h, m1[9]);
            m0[10] = __hfma2(wh0, cc.h, m0[10]);   m1[10] = __hfma2(wh1, cc.h, m1[10]);
        }
        w0r = nw0;
        w1r = nw1;
    }

#ifdef USE_UDOT
    float ws0 = (float)ws0i, ws1 = (float)ws1i;
#else
    float ws0 = ws0f, ws1 = ws1f;
#endif

    // Epilogue (log2-domain softmax). Messages and wsum are both x255-scaled;
    // msg/wsum is invariant; 1e-8 rescales to 2.55e-6.
    unsigned int* Qo = Qn + (size_t)b * NP * HW;

    float nll = 0.f;
#pragma unroll
    for (int px = 0; px < 2; ++px) {
        const __half2* m = px ? m1 : m0;
        float inv = 1.f / ((px ? ws1 : ws0) + 2.55e-6f);
        int g = g0 + px * W;
        float sv[C];
        float mm = -1e30f;
#pragma unroll
        for (int k = 0; k < NP; ++k) {
            float2 mf = __half22float2(m[k]);
            Hu mgu; mgu.u32 = pfM[px][k];
            float2 mgf = __half22float2(mgu.h);
            Hu uu; uu.u32 = pfU[px][k];
            float2 uf = __half22float2(uu.h);
            int c0 = 2 * k;
            float v0 = fmaf(-L2E, uf.x, fmaf(3.f*L2E, mgf.x, (10.f*L2E) * (mf.x * inv)));
            sv[c0] = v0; mm = fmaxf(mm, v0);
            if (c0 + 1 < C) {
                float v1 = fmaf(-L2E, uf.y, fmaf(3.f*L2E, mgf.y, (10.f*L2E) * (mf.y * inv)));
                sv[c0+1] = v1; mm = fmaxf(mm, v1);
            }
        }
        float s = 0.f;
#pragma unroll
        for (int c = 0; c < C; ++c) { sv[c] = fexp2(sv[c] - mm); s += sv[c]; }
        if (labels) {
            int lab = labels[(size_t)b * HW + g];
            float qsum = 0.f, ql = 1e-8f;
#pragma unroll
            for (int c = 0; c < C; ++c) {
                float qc = sv[c] / s + 1e-8f;
                qsum += qc;
                if (c == lab) ql = qc;
            }
            nll += __logf(qsum) - __logf(ql);
        } else {
            float is = 1.f / s;
#pragma unroll
            for (int k = 0; k < NP; ++k) {
                float a = sv[2*k] * is;
                float bb = (2*k + 1 < C) ? sv[2*k + 1] * is : 0.f;
                Hu xh; xh.h = __floats2half2_rn(a, bb);
                Qo[k*HW + g] = xh.u32;
            }
        }
    }

    if (labels) {
#pragma unroll
        for (int off = 32; off > 0; off >>= 1) nll += __shfl_down(nll, off);
        int lane = tid & 63, wv = tid >> 6;
        if (lane == 0) red[wv] = nll;
        __syncthreads();
        if (tid == 0) part[blk] = red[0] + red[1] + red[2] + red[3];
    }
}

// ---------------------------------------------------------------------------
__global__ __launch_bounds__(256) void k_final(const float* __restrict__ part,
                                               float* __restrict__ out) {
    int tid = threadIdx.x;
    float s = part[tid] + part[tid + 256];
#pragma unroll
    for (int off = 32; off > 0; off >>= 1) s += __shfl_down(s, off);
    __shared__ float red[4];
    int lane = tid & 63, wv = tid >> 6;
    if (lane == 0) red[wv] = s;
    __syncthreads();
    if (tid == 0) out[0] = (red[0] + red[1] + red[2] + red[3]) / (float)NPIX;
}

// ---------------------------------------------------------------------------
extern "C" void kernel_launch(void* const* d_in, const int* in_sizes, int n_in,
                              void* d_out, int out_size, void* d_ws, size_t ws_size,
                              hipStream_t stream) {
    const float* logits = (const float*)d_in[0];
    const float* images = (const float*)d_in[1];
    const int*   labels = (const int*)d_in[2];
    float* out = (float*)d_out;

    unsigned int* ws = (unsigned int*)d_ws;
    unsigned int* Upk = ws;                     // NB2
    unsigned int* QA  = ws +   (size_t)NB2;     // NB2
    unsigned int* QB  = ws + 2*(size_t)NB2;     // NB2
    unsigned int* Mpk = ws + 3*(size_t)NB2;     // NB2
    uint4*        WT  = (uint4*)(ws + 4*(size_t)NB2);        // 512*15*512 uint4 = 62.9MB
    float*        KT  = (float*)(WT + (size_t)512*WT_TILE);  // 64 f32
    float*        PART = KT + 64;                            // 512 f32

    k_init<<<NPIX/256, 256, 0, stream>>>(logits, Upk, QA, KT);
    k_wgt<<<B*128, 256, 0, stream>>>(images, WT);

    unsigned int* cur = QA;
    unsigned int* oth = QB;
    for (int it = 0; it < 5; ++it) {
        k_gauss<<<B*NP*16, 256, 0, stream>>>(cur, Mpk, KT);
        k_update<<<B*128, 256, 0, stream>>>(cur, Upk, Mpk, WT, oth,
                                            (it == 4) ? labels : nullptr, PART);
        unsigned int* t = cur; cur = oth; oth = t;
    }

    k_final<<<1, 256, 0, stream>>>(PART, out);
    (void)in_sizes; (void)n_in; (void)out_size; (void)ws_size;
}

// Round 13
// 289.767 us; speedup vs baseline: 1.6461x; 1.0126x over previous
//
#include <hip/hip_runtime.h>
#include <hip/hip_fp16.h>
#include <math.h>

// Problem constants
#define B 4
#define C 21
#define NP 11               // f16 channel pairs (ch 2k, 2k+1; pair 10 high = pad)
#define H 256
#define W 256
#define HW (H*W)            // 65536
#define NPIX (B*HW)         // 262144
#define NB2 (B*NP*HW)       // 2883584 packed uint elements

// update tile: 16 wide x 32 tall, 256 threads, 2 rows per thread
#define TSX 16
#define TSY 32
#define R 6
#define HXC 28              // halo cols
#define HYR 44              // halo rows
#define NSU (HXC*HYR)       // 1232 records
#define NSP (NSU + HXC)     // +1 pad row for pipelined prefetch overrun

#define C2F ((float)(1.4426950408889634 / 338.0))   // log2(e)/338
#define L2E 1.4426950408889634f

// weight table: [tile(512)][15 rows][512 px][16B]; rows 13,14 zeroed (pipeline pad)
#define WT_ROWS 15
#define WT_TILE (WT_ROWS*512)    // uint4 per tile

// Gaussian-fused kernel geometry
#define GOY 64
#define GTR (GOY + 18)      // 82 T rows
#define GTS 17              // padded quad stride

union U4 { uint4 u; __half2 h[4]; };
union Hu { unsigned int u32; __half2 h; };

#if defined(__has_builtin)
#if __has_builtin(__builtin_amdgcn_udot4)
#define USE_UDOT 1
#endif
#endif

__device__ __forceinline__ float fexp2(float x) {
    float r;
    asm("v_exp_f32 %0, %1" : "=v"(r) : "v"(x));
    return r;
}

typedef __fp16 f16x2 __attribute__((ext_vector_type(2)));
__device__ __forceinline__ __half2 h2bcast(float w) {
    f16x2 t = __builtin_amdgcn_cvt_pkrtz(w, w);   // exact: w is an integer 0..255
    return *(__half2*)&t;
}

// ---------------------------------------------------------------------------
// Init: U = -log(clip(softmax(logits),1e-5,1)) packed f16; Q0 = softmax(-U).
// Thread 0 of block 0 also fills the Gaussian tap table.
__global__ __launch_bounds__(256) void k_init(const float* __restrict__ logits,
                                              unsigned int* __restrict__ Upk,
                                              unsigned int* __restrict__ Qp,
                                              float* __restrict__ kt) {
    int p = blockIdx.x * 256 + threadIdx.x;
    if (p == 0) {
        float e[19]; float s0 = 0.f;
        for (int i = 0; i < 19; ++i) {
            double d = (double)(i - 9);
            e[i] = (float)exp(-(d*d) / 18.0);
            s0 += e[i];
        }
        for (int i = 0; i < 19; ++i) kt[i] = e[i] / s0;
        float k9 = e[9] / s0;
        kt[19] = k9 * k9;
        kt[20] = 1.f - k9 * k9;
    }
    int b = p >> 16, g = p & (HW - 1);
    const float* lp = logits + (size_t)b * C * HW + g;

    float v[C];
    float m = -1e30f;
#pragma unroll
    for (int c = 0; c < C; ++c) { v[c] = lp[c*HW]; m = fmaxf(m, v[c]); }
    float s = 0.f;
#pragma unroll
    for (int c = 0; c < C; ++c) { v[c] = __expf(v[c] - m); s += v[c]; }
    float inv = 1.f / s;

    float u[C];
    float m2 = -1e30f;
#pragma unroll
    for (int c = 0; c < C; ++c) {
        float sm = fminf(fmaxf(v[c] * inv, 1e-5f), 1.f);
        float uu = -__logf(sm);
        u[c] = uu;
        m2 = fmaxf(m2, -uu);
    }
    float s2 = 0.f;
    float q[C];
#pragma unroll
    for (int c = 0; c < C; ++c) { q[c] = __expf(-u[c] - m2); s2 += q[c]; }
    float inv2 = 1.f / s2;

    unsigned int* Ub = Upk + (size_t)b * NP * HW + g;
    unsigned int* Qb = Qp + (size_t)b * NP * HW + g;
#pragma unroll
    for (int k = 0; k < NP; ++k) {
        float ua = u[2*k];
        float ub = (2*k + 1 < C) ? u[2*k + 1] : 0.f;
        Hu xu; xu.h = __floats2half2_rn(ua, ub);
        Ub[k*HW] = xu.u32;
        float qa = q[2*k] * inv2;
        float qb = (2*k + 1 < C) ? q[2*k + 1] * inv2 : 0.f;
        Hu xq; xq.h = __floats2half2_rn(qa, qb);
        Qb[k*HW] = xq.u32;
    }
}

// ---------------------------------------------------------------------------
// Precompute bilateral weights (image-only, iteration-invariant), u8-quantized.
// WT[tile][row 0..12][px 0..511] = uint4 of 13 weights; rows 13,14 zeroed.
__global__ __launch_bounds__(256) void k_wgt(const float* __restrict__ img,
                                             uint4* __restrict__ WT) {
    __shared__ float4 IRGB[NSU];    // quantized rgb halo, 19.7KB

    int blk = blockIdx.x;
    int b = blk >> 7;
    int tile = blk & 127;
    int ty0 = (tile >> 4) * TSY;
    int tx0 = (tile & 15) * TSX;
    int tid = threadIdx.x;

    const float* Ib = img + (size_t)b * 3 * HW;
    for (int s = tid; s < NSU; s += 256) {
        int ly = s / HXC, lx = s - ly * HXC;
        int gy = ty0 + ly - R, gx = tx0 + lx - R;
        bool in = ((unsigned)gy < (unsigned)H) && ((unsigned)gx < (unsigned)W);
        int g = gy * W + gx;
        float r = 0.f, gg = 0.f, bb = 0.f;
        if (in) {
            r  = floorf(fminf(fmaxf(Ib[g]        * 255.f, 0.f), 255.f));
            gg = floorf(fminf(fmaxf(Ib[HW + g]   * 255.f, 0.f), 255.f));
            bb = floorf(fminf(fmaxf(Ib[2*HW + g] * 255.f, 0.f), 255.f));
        }
        IRGB[s] = make_float4(r, gg, bb, 0.f);
    }
    __syncthreads();

    int x = tid & 15, ry = tid >> 4, r0 = 2 * ry;
    int cp0 = (r0 + R) * HXC + x + R;
    float4 c0 = IRGB[cp0];
    float4 c1 = IRGB[cp0 + HXC];
    float DCr = c1.x - c0.x, DCg = c1.y - c0.y, DCb = c1.z - c0.z;
    float DR2 = 2.f*DCr, DG2 = 2.f*DCg, DB2 = 2.f*DCb;
    float DC2 = DCr*DCr + DCg*DCg + DCb*DCb;

    uint4* base = WT + (size_t)blk * WT_TILE;
    int px0 = r0 * 16 + x;

    for (int dyy = 0; dyy < 14; ++dyy) {
        int t0 = dyy - 6, t1 = dyy - 7;
        float a0 = -(float)(t0*t0) * C2F;
        float a1 = -(float)(t1*t1) * C2F;
        unsigned int wa0[4] = {0u,0u,0u,0u}, wa1[4] = {0u,0u,0u,0u};
        int rowb = (r0 + dyy) * HXC + x;
#pragma unroll
        for (int dx = 0; dx < 13; ++dx) {
            float4 n = IRGB[rowb + dx];
            float d0r = c0.x - n.x, d0g = c0.y - n.y, d0b = c0.z - n.z;
            float ss0 = fmaf(d0r, d0r, fmaf(d0g, d0g, d0b * d0b));
            float ss1 = fmaf(DR2, d0r, fmaf(DG2, d0g, fmaf(DB2, d0b, ss0 + DC2)));
            float cc = -(float)((dx - 6) * (dx - 6)) * C2F;
            float w0 = fexp2(fmaf(ss0, -C2F, a0 + cc));
            float w1 = fexp2(fmaf(ss1, -C2F, a1 + cc));
            if (dyy == 6 && dx == 6) w0 = 0.f;   // exact center exclusion
            if (dyy == 7 && dx == 6) w1 = 0.f;
            unsigned int u0 = (unsigned int)fmaf(w0, 255.f, 0.5f);
            unsigned int u1 = (unsigned int)fmaf(w1, 255.f, 0.5f);
            wa0[dx >> 2] |= u0 << (8 * (dx & 3));
            wa1[dx >> 2] |= u1 << (8 * (dx & 3));
        }
        if (dyy <= 12) base[dyy*512 + px0]          = make_uint4(wa0[0], wa0[1], wa0[2], wa0[3]);
        if (dyy >= 1)  base[(dyy-1)*512 + px0 + 16] = make_uint4(wa1[0], wa1[1], wa1[2], wa1[3]);
    }
    // zero pipeline-pad rows 13,14 (each thread covers px0 and px0+16)
    uint4 z = make_uint4(0u, 0u, 0u, 0u);
    base[13*512 + px0] = z;  base[13*512 + px0 + 16] = z;
    base[14*512 + px0] = z;  base[14*512 + px0 + 16] = z;
}

// ---------------------------------------------------------------------------
// Fused separable Gaussian + message: MG = (conv - w0*Q)*(1/(1-w0)).
__global__ __launch_bounds__(256) void k_gauss(const unsigned int* __restrict__ Q,
                                               unsigned int* __restrict__ MG,
                                               const float* __restrict__ kt) {
    __shared__ uint4 T[GTR * GTS];
    __shared__ float kf[21];

    int tid = threadIdx.x;
    if (tid < 21) kf[tid] = kt[tid];
    __syncthreads();

    __half2 kh[19];
#pragma unroll
    for (int j = 0; j < 19; ++j) kh[j] = __float2half2_rn(kf[j]);

    int blk = blockIdx.x;
    int pl  = blk >> 4;
    int sub = blk & 15;
    int y0 = (sub >> 2) * GOY;
    int x0 = (sub & 3) * 64;
    const unsigned int* base = Q + (size_t)pl * HW;

    for (int s = tid; s < GTR * 16; s += 256) {
        int row = s >> 4;
        int q   = s & 15;
        int yy = y0 + row - 9;
        U4 o;
        o.u = make_uint4(0u, 0u, 0u, 0u);
        if ((unsigned)yy < (unsigned)H) {
            int xb = x0 + q * 4;
            const unsigned int* rp = base + yy * W;
            U4 ch[7];
#pragma unroll
            for (int c2 = 0; c2 < 7; ++c2) {
                int xq = xb - 12 + c2 * 4;
                if ((unsigned)xq < (unsigned)W) ch[c2].u = *(const uint4*)(rp + xq);
                else ch[c2].u = make_uint4(0u, 0u, 0u, 0u);
            }
            const __half2* v = (const __half2*)ch;
#pragma unroll
            for (int i = 0; i < 4; ++i) {
                __half2 acc = __float2half2_rn(0.f);
#pragma unroll
                for (int j = 0; j < 19; ++j) acc = __hfma2(kh[j], v[i + 3 + j], acc);
                o.h[i] = acc;
            }
        }
        T[row * GTS + q] = o.u;
    }
    __syncthreads();

    __half2 nw0  = __float2half2_rn(-kf[19]);
    __half2 inv1 = __float2half2_rn(1.f / kf[20]);
    int q  = tid & 15;
    int rg = tid >> 4;
    int r0 = rg * 4;

    __half2 acc[4][4];
#pragma unroll
    for (int i = 0; i < 4; ++i)
#pragma unroll
        for (int qd = 0; qd < 4; ++qd) acc[i][qd] = __float2half2_rn(0.f);

#pragma unroll
    for (int j = 0; j < 22; ++j) {
        U4 f; f.u = T[(r0 + j) * GTS + q];
#pragma unroll
        for (int i = 0; i < 4; ++i) {
            int tap = j - i;
            if (tap >= 0 && tap <= 18) {
#pragma unroll
                for (int qd = 0; qd < 4; ++qd)
                    acc[i][qd] = __hfma2(kh[tap], f.h[qd], acc[i][qd]);
            }
        }
    }

#pragma unroll
    for (int i = 0; i < 4; ++i) {
        size_t e = (size_t)pl * HW + (y0 + r0 + i) * W + x0 + q * 4;
        U4 qq; qq.u = *(const uint4*)(Q + e);
        U4 o;
#pragma unroll
        for (int qd = 0; qd < 4; ++qd)
            o.h[qd] = __hmul2(__hfma2(nw0, qq.h[qd], acc[i][qd]), inv1);
        *(uint4*)(MG + e) = o.u;
    }
}

// ---------------------------------------------------------------------------
// Bilateral message (precomputed u8 weights) + mean-field update, 2 px/thread.
// Depth-2 software pipeline: tap t+1's three LDS records load while tap t's
// 22 pk-FMAs execute. Pad row keeps the final discarded prefetch in-bounds.
__global__ __launch_bounds__(256, 2) void k_update(const unsigned int* __restrict__ Q,
                                                   const unsigned int* __restrict__ Upk,
                                                   const unsigned int* __restrict__ MG,
                                                   const uint4* __restrict__ WT,
                                                   unsigned int* __restrict__ Qn,
                                                   const int* __restrict__ labels,
                                                   float* __restrict__ part) {
    __shared__ uint4 LA[NSP];   // ch 0..7   (20160 B)
    __shared__ uint4 LB[NSP];   // ch 8..15  (20160 B)
    __shared__ uint4 LC4[NSP];  // ch 16..20 + pad (20160 B) -> total 60.5 KB
    __shared__ float red[4];

    int blk = blockIdx.x;
    int b = blk >> 7;
    int tile = blk & 127;
    int ty0 = (tile >> 4) * TSY;
    int tx0 = (tile & 15) * TSX;
    int tid = threadIdx.x;

    const unsigned int* Qb = Q + (size_t)b * NP * HW;

    // explicit 5-step staging (compile-time trip count -> batched loads)
#pragma unroll
    for (int i = 0; i < 5; ++i) {
        int s = tid + i * 256;
        if (s < NSU) {
            int ly = s / HXC;
            int lx = s - ly * HXC;
            int gy = ty0 + ly - R;
            int gx = tx0 + lx - R;
            bool in = ((unsigned)gy < (unsigned)H) && ((unsigned)gx < (unsigned)W);
            int g = gy * W + gx;
            unsigned int u[NP];
#pragma unroll
            for (int k = 0; k < NP; ++k) u[k] = in ? Qb[k*HW + g] : 0u;
            LA[s]  = make_uint4(u[0], u[1], u[2], u[3]);
            LB[s]  = make_uint4(u[4], u[5], u[6], u[7]);
            LC4[s] = make_uint4(u[8], u[9], u[10], 0u);
        }
    }
    __syncthreads();

    int x = tid & 15;
    int ry = tid >> 4;                // 0..15 -> rows 2ry, 2ry+1
    int r0 = 2 * ry;
    int g0 = (ty0 + r0) * W + (tx0 + x);
    int px0 = r0 * 16 + x;

    // epilogue prefetch
    const unsigned int* Ub = Upk + (size_t)b * NP * HW;
    const unsigned int* Mb = MG + (size_t)b * NP * HW;
    unsigned int pfU[2][NP], pfM[2][NP];
#pragma unroll
    for (int k = 0; k < NP; ++k) {
        pfU[0][k] = Ub[k*HW + g0];       pfM[0][k] = Mb[k*HW + g0];
        pfU[1][k] = Ub[k*HW + g0 + W];   pfM[1][k] = Mb[k*HW + g0 + W];
    }

    const uint4* wbase = WT + (size_t)blk * WT_TILE;

    __half2 m0[NP], m1[NP];
#pragma unroll
    for (int k = 0; k < NP; ++k) { m0[k] = __float2half2_rn(0.f); m1[k] = m0[k]; }
#ifdef USE_UDOT
    unsigned int ws0i = 0u, ws1i = 0u;
#else
    float ws0f = 0.f, ws1f = 0.f;
#endif

    // software-pipelined weight rows + depth-2 record rotation
    uint4 w0r = wbase[px0];                 // w0 row 0
    uint4 w1r = make_uint4(0u, 0u, 0u, 0u); // w1 row -1 = zero

    int pp0 = r0 * HXC + x;
    U4 Ac, Bc, Cc;
    Ac.u = LA[pp0]; Bc.u = LB[pp0]; Cc.u = LC4[pp0];

    for (int dyy = 0; dyy < 14; ++dyy) {
        uint4 nw0 = wbase[(dyy + 1) * 512 + px0];        // rows 1..14 (13,14 zero)
        uint4 nw1 = wbase[dyy * 512 + px0 + 16];         // w1 rows 0..13 (13 zero)
#ifdef USE_UDOT
        ws0i = __builtin_amdgcn_udot4(w0r.x, 0x01010101u, ws0i, false);
        ws0i = __builtin_amdgcn_udot4(w0r.y, 0x01010101u, ws0i, false);
        ws0i = __builtin_amdgcn_udot4(w0r.z, 0x01010101u, ws0i, false);
        ws0i = __builtin_amdgcn_udot4(w0r.w, 0x01010101u, ws0i, false);
        ws1i = __builtin_amdgcn_udot4(w1r.x, 0x01010101u, ws1i, false);
        ws1i = __builtin_amdgcn_udot4(w1r.y, 0x01010101u, ws1i, false);
        ws1i = __builtin_amdgcn_udot4(w1r.z, 0x01010101u, ws1i, false);
        ws1i = __builtin_amdgcn_udot4(w1r.w, 0x01010101u, ws1i, false);
#endif
        int rowb = (r0 + dyy) * HXC + x;
#pragma unroll
        for (int dx = 0; dx < 13; ++dx) {
            // prefetch next tap (next record in row, or first record of next row)
            int pn = (dx < 12) ? (rowb + dx + 1) : (rowb + HXC);
            U4 An, Bn, Cn;
            An.u = LA[pn]; Bn.u = LB[pn]; Cn.u = LC4[pn];

            unsigned int q0 = (dx < 4) ? w0r.x : (dx < 8) ? w0r.y : (dx < 12) ? w0r.z : w0r.w;
            unsigned int q1 = (dx < 4) ? w1r.x : (dx < 8) ? w1r.y : (dx < 12) ? w1r.z : w1r.w;
            float w0 = (float)((q0 >> (8 * (dx & 3))) & 0xffu);   // v_cvt_f32_ubyteN
            float w1 = (float)((q1 >> (8 * (dx & 3))) & 0xffu);
#ifndef USE_UDOT
            ws0f += w0; ws1f += w1;
#endif
            __half2 wh0 = h2bcast(w0);
            __half2 wh1 = h2bcast(w1);
            m0[0] = __hfma2(wh0, Ac.h[0], m0[0]);   m1[0] = __hfma2(wh1, Ac.h[0], m1[0]);
            m0[1] = __hfma2(wh0, Ac.h[1], m0[1]);   m1[1] = __hfma2(wh1, Ac.h[1], m1[1]);
            m0[2] = __hfma2(wh0, Ac.h[2], m0[2]);   m1[2] = __hfma2(wh1, Ac.h[2], m1[2]);
            m0[3] = __hfma2(wh0, Ac.h[3], m0[3]);   m1[3] = __hfma2(wh1, Ac.h[3], m1[3]);
            m0[4] = __hfma2(wh0, Bc.h[0], m0[4]);   m1[4] = __hfma2(wh1, Bc.h[0], m1[4]);
            m0[5] = __hfma2(wh0, Bc.h[1], m0[5]);   m1[5] = __hfma2(wh1, Bc.h[1], m1[5]);
            m0[6] = __hfma2(wh0, Bc.h[2], m0[6]);   m1[6] = __hfma2(wh1, Bc.h[2], m1[6]);
            m0[7] = __hfma2(wh0, Bc.h[3], m0[7]);   m1[7] = __hfma2(wh1, Bc.h[3], m1[7]);
            m0[8] = __hfma2(wh0, Cc.h[0], m0[8]);   m1[8] = __hfma2(wh1, Cc.h[0], m1[8]);
            m0[9] = __hfma2(wh0, Cc.h[1], m0[9]);   m1[9] = __hfma2(wh1, Cc.h[1], m1[9]);
            m0[10] = __hfma2(wh0, Cc.h[2], m0[10]); m1[10] = __hfma2(wh1, Cc.h[2], m1[10]);

            Ac = An; Bc = Bn; Cc = Cn;
        }
        w0r = nw0;
        w1r = nw1;
    }

#ifdef USE_UDOT
    float ws0 = (float)ws0i, ws1 = (float)ws1i;
#else
    float ws0 = ws0f, ws1 = ws1f;
#endif

    // Epilogue (log2-domain softmax). Messages and wsum are both x255-scaled;
    // msg/wsum is invariant; 1e-8 rescales to 2.55e-6.
    unsigned int* Qo = Qn + (size_t)b * NP * HW;

    float nll = 0.f;
#pragma unroll
    for (int px = 0; px < 2; ++px) {
        const __half2* m = px ? m1 : m0;
        float inv = 1.f / ((px ? ws1 : ws0) + 2.55e-6f);
        int g = g0 + px * W;
        float sv[C];
        float mm = -1e30f;
#pragma unroll
        for (int k = 0; k < NP; ++k) {
            float2 mf = __half22float2(m[k]);
            Hu mgu; mgu.u32 = pfM[px][k];
            float2 mgf = __half22float2(mgu.h);
            Hu uu; uu.u32 = pfU[px][k];
            float2 uf = __half22float2(uu.h);
            int c0 = 2 * k;
            float v0 = fmaf(-L2E, uf.x, fmaf(3.f*L2E, mgf.x, (10.f*L2E) * (mf.x * inv)));
            sv[c0] = v0; mm = fmaxf(mm, v0);
            if (c0 + 1 < C) {
                float v1 = fmaf(-L2E, uf.y, fmaf(3.f*L2E, mgf.y, (10.f*L2E) * (mf.y * inv)));
                sv[c0+1] = v1; mm = fmaxf(mm, v1);
            }
        }
        float s = 0.f;
#pragma unroll
        for (int c = 0; c < C; ++c) { sv[c] = fexp2(sv[c] - mm); s += sv[c]; }
        if (labels) {
            int lab = labels[(size_t)b * HW + g];
            float qsum = 0.f, ql = 1e-8f;
#pragma unroll
            for (int c = 0; c < C; ++c) {
                float qc = sv[c] / s + 1e-8f;
                qsum += qc;
                if (c == lab) ql = qc;
            }
            nll += __logf(qsum) - __logf(ql);
        } else {
            float is = 1.f / s;
#pragma unroll
            for (int k = 0; k < NP; ++k) {
                float a = sv[2*k] * is;
                float bb = (2*k + 1 < C) ? sv[2*k + 1] * is : 0.f;
                Hu xh; xh.h = __floats2half2_rn(a, bb);
                Qo[k*HW + g] = xh.u32;
            }
        }
    }

    if (labels) {
#pragma unroll
        for (int off = 32; off > 0; off >>= 1) nll += __shfl_down(nll, off);
        int lane = tid & 63, wv = tid >> 6;
        if (lane == 0) red[wv] = nll;
        __syncthreads();
        if (tid == 0) part[blk] = red[0] + red[1] + red[2] + red[3];
    }
}

// ---------------------------------------------------------------------------
__global__ __launch_bounds__(256) void k_final(const float* __restrict__ part,
                                               float* __restrict__ out) {
    int tid = threadIdx.x;
    float s = part[tid] + part[tid + 256];
#pragma unroll
    for (int off = 32; off > 0; off >>= 1) s += __shfl_down(s, off);
    __shared__ float red[4];
    int lane = tid & 63, wv = tid >> 6;
    if (lane == 0) red[wv] = s;
    __syncthreads();
    if (tid == 0) out[0] = (red[0] + red[1] + red[2] + red[3]) / (float)NPIX;
}

// ---------------------------------------------------------------------------
extern "C" void kernel_launch(void* const* d_in, const int* in_sizes, int n_in,
                              void* d_out, int out_size, void* d_ws, size_t ws_size,
                              hipStream_t stream) {
    const float* logits = (const float*)d_in[0];
    const float* images = (const float*)d_in[1];
    const int*   labels = (const int*)d_in[2];
    float* out = (float*)d_out;

    unsigned int* ws = (unsigned int*)d_ws;
    unsigned int* Upk = ws;                     // NB2
    unsigned int* QA  = ws +   (size_t)NB2;     // NB2
    unsigned int* QB  = ws + 2*(size_t)NB2;     // NB2
    unsigned int* Mpk = ws + 3*(size_t)NB2;     // NB2
    uint4*        WT  = (uint4*)(ws + 4*(size_t)NB2);        // 512*15*512 uint4 = 62.9MB
    float*        KT  = (float*)(WT + (size_t)512*WT_TILE);  // 64 f32
    float*        PART = KT + 64;                            // 512 f32

    k_init<<<NPIX/256, 256, 0, stream>>>(logits, Upk, QA, KT);
    k_wgt<<<B*128, 256, 0, stream>>>(images, WT);

    unsigned int* cur = QA;
    unsigned int* oth = QB;
    for (int it = 0; it < 5; ++it) {
        k_gauss<<<B*NP*16, 256, 0, stream>>>(cur, Mpk, KT);
        k_update<<<B*128, 256, 0, stream>>>(cur, Upk, Mpk, WT, oth,
                                            (it == 4) ? labels : nullptr, PART);
        unsigned int* t = cur; cur = oth; oth = t;
    }

    k_final<<<1, 256, 0, stream>>>(PART, out);
    (void)in_sizes; (void)n_in; (void)out_size; (void)ws_size;
}